// Round 15
// baseline (587.546 us; speedup 1.0000x reference)
//
#include <hip/hip_runtime.h>

#define N_NODES  100000
#define N_EDGES  1600000
#define HIDDEN   128
#define STEPS    4
#define N_GRAPHS 64
#define NBUCK    256
#define BWID     391   // nodes per bucket: 256*391 = 100096 >= 100000 (<512 -> 9 bits)
#define BCAP     7168  // fixed ebuf slots per bucket (mean 6250, +11 sigma)

typedef unsigned short u16;
typedef unsigned int   u32;
typedef unsigned long long u64;
typedef __attribute__((ext_vector_type(8))) short bf16x8;
typedef __attribute__((ext_vector_type(4))) float f32x4;
typedef __attribute__((ext_vector_type(2))) float f32x2;

__device__ inline u16 f2bf(float f) {
  u32 u = __float_as_uint(f);
  u = (u + 0x7FFFu + ((u >> 16) & 1u)) >> 16;  // RTNE
  return (u16)u;
}
__device__ inline float bf2f(u16 b) { return __uint_as_float(((u32)b) << 16); }

// rcp-based activations: no IEEE division sequence, no clamps.
__device__ inline float rcp_f(float x) { return __builtin_amdgcn_rcpf(x); }
__device__ inline float sig_f(float x) { return rcp_f(1.f + __expf(-x)); }
__device__ inline float tanh_f(float x) { return 1.f - 2.f * rcp_f(1.f + __expf(2.f * x)); }

// ---------------- CSR build (bucketed multisplit, fixed-capacity buckets) ----------------
// ebuf entries are u32: (dst_local << 17) | src   (dst_local < 391, src < 2^17)
__global__ __launch_bounds__(1024) void k_part(const int* __restrict__ esrc,
                                               const int* __restrict__ edst,
                                               int* __restrict__ gcursor,
                                               u32* __restrict__ ebuf) {
  __shared__ int hist[NBUCK];
  __shared__ int base[NBUCK];
  int tid = threadIdx.x;
  if (tid < NBUCK) hist[tid] = 0;
  __syncthreads();
  int e0 = blockIdx.x * 4096;
  int sv[4], dv[4], bk[4], rk[4];
  #pragma unroll
  for (int i = 0; i < 4; ++i) {
    int e = e0 + i * 1024 + tid;
    if (e < N_EDGES) {
      sv[i] = esrc[e];
      dv[i] = edst[e];
      bk[i] = (int)((u32)dv[i] / (u32)BWID);
      rk[i] = atomicAdd(&hist[bk[i]], 1);
    } else bk[i] = -1;
  }
  __syncthreads();
  if (tid < NBUCK) base[tid] = atomicAdd(&gcursor[tid], hist[tid]);
  __syncthreads();
  #pragma unroll
  for (int i = 0; i < 4; ++i) {
    if (bk[i] >= 0) {
      int pos = bk[i] * BCAP + base[bk[i]] + rk[i];
      ebuf[pos] = ((u32)(dv[i] - bk[i] * BWID) << 17) | (u32)sv[i];
    }
  }
}

__global__ void k_bscan(const int* __restrict__ gcursor, int* __restrict__ ebase) {
  __shared__ int buf[NBUCK];
  int t = threadIdx.x;
  int v = gcursor[t];
  buf[t] = v;
  __syncthreads();
  for (int off = 1; off < NBUCK; off <<= 1) {
    int u = 0;
    if (t >= off) u = buf[t - off];
    __syncthreads();
    buf[t] += u;
    __syncthreads();
  }
  ebase[t] = buf[t] - v;
  if (t == NBUCK - 1) ebase[NBUCK] = buf[t];
}

__global__ __launch_bounds__(1024) void k_csr(const u32* __restrict__ ebuf,
                                              const int* __restrict__ ebase,
                                              int* __restrict__ offs,
                                              int* __restrict__ csr) {
  __shared__ int lcnt[512];
  __shared__ int lofs[512];
  int b = blockIdx.x, tid = threadIdx.x;
  int n0 = b * BWID;
  int n1 = min(n0 + BWID, N_NODES);
  int nn = n1 - n0;
  int e0 = ebase[b];
  int cnt = ebase[b + 1] - e0;
  const u32* ebase_p = ebuf + (size_t)b * BCAP;
  if (tid < 512) lcnt[tid] = 0;
  __syncthreads();
  for (int e = tid; e < cnt; e += 1024) {
    int dst = (int)(ebase_p[e] >> 17);   // bucket-local
    atomicAdd(&lcnt[dst], 1);
  }
  __syncthreads();
  if (tid < 512) lofs[tid] = lcnt[tid];
  __syncthreads();
  for (int off = 1; off < 512; off <<= 1) {
    int v = 0;
    if (tid < 512 && tid >= off) v = lofs[tid - off];
    __syncthreads();
    if (tid < 512 && tid >= off) lofs[tid] += v;
    __syncthreads();
  }
  int nodeoff = 0;
  if (tid < 512) nodeoff = e0 + lofs[tid] - lcnt[tid];  // exclusive
  if (tid < 512) lofs[tid] = nodeoff;                   // reuse as cursor
  if (tid < nn) offs[n0 + tid] = nodeoff;
  if (b == 0 && tid == 0) offs[N_NODES] = N_EDGES;
  __syncthreads();
  for (int e = tid; e < cnt; e += 1024) {
    u32 p = ebase_p[e];
    int src = (int)(p & 0x1FFFFu);
    int dst = (int)(p >> 17);
    int pos = atomicAdd(&lofs[dst], 1);
    csr[pos] = src;
  }
}

// ---------------- combined weight build ----------------
__global__ void k_wb(const float* __restrict__ W, const float* __restrict__ w_ih,
                     const float* __restrict__ w_hh, u16* __restrict__ bsw) {
  __shared__ float wrow[128];
  int b = blockIdx.x, st = b >> 8, k = b & 255, t = threadIdx.x;
  if (k < 128) wrow[t] = W[(st * 128 + k) * 128 + t];
  __syncthreads();
  int kc = k >> 5, quad = (k >> 3) & 3, kl = k & 7;
  u16* base = bsw + (size_t)st * 131072 + kc * 16384;
  #pragma unroll
  for (int gq = 0; gq < 4; ++gq) {
    int c = gq * 128 + t;
    float v;
    if (k < 128) {
      if (c < 384) {
        const float* wr = w_ih + c * 128;
        float sacc = 0.f;
        for (int j = 0; j < 128; ++j) sacc += wrow[j] * wr[j];
        v = sacc;
      } else v = 0.f;
    } else {
      int kk = k - 128;
      if (c < 256)      v = w_hh[c * 128 + kk];
      else if (c < 384) v = 0.f;
      else              v = w_hh[(c - 128) * 128 + kk];
    }
    int gi = c >> 7, cw = c & 127;
    int wv = cw >> 5, hu = (cw >> 4) & 1, nl = c & 15;
    int slot = wv * 8 + gi * 2 + hu;
    base[(slot * 4 + quad) * 128 + nl * 8 + kl] = f2bf(v);
  }
}

// ---------------- x -> bf16 ----------------
__global__ void k_convert(const float* __restrict__ x, u16* __restrict__ h) {
  int i = (blockIdx.x * 256 + threadIdx.x) * 4;
  float4 v = *(const float4*)(x + i);
  u16 o[4] = {f2bf(v.x), f2bf(v.y), f2bf(v.z), f2bf(v.w)};
  *(uint2*)(h + i) = *(uint2*)o;
}

// ---------------- neighbor gather-sum: s[dst] = sum h[src] (R13-proven) ----------------
__device__ inline void acc8(f32x2* a, uint4 p) {
  f32x2 v;
  v.x = __uint_as_float(p.x << 16); v.y = __uint_as_float(p.x & 0xffff0000u);
  a[0] += v;
  v.x = __uint_as_float(p.y << 16); v.y = __uint_as_float(p.y & 0xffff0000u);
  a[1] += v;
  v.x = __uint_as_float(p.z << 16); v.y = __uint_as_float(p.z & 0xffff0000u);
  a[2] += v;
  v.x = __uint_as_float(p.w << 16); v.y = __uint_as_float(p.w & 0xffff0000u);
  a[3] += v;
}

__global__ void k_gather(const u16* __restrict__ h, const int* __restrict__ csr,
                         const int* __restrict__ offs, u16* __restrict__ s) {
  int node = blockIdx.x * 4 + (threadIdx.x >> 6);
  int lane = threadIdx.x & 63;
  int q   = lane >> 4;
  int sub = lane & 15;
  int beg = offs[node], end = offs[node + 1];
  f32x2 a[4];
  a[0] = a[1] = a[2] = a[3] = (f32x2){0.f, 0.f};
  int j = beg + q;
  for (; j + 12 < end; j += 16) {
    int s0 = csr[j], s1 = csr[j + 4], s2 = csr[j + 8], s3 = csr[j + 12];
    uint4 p0 = *(const uint4*)(h + (size_t)s0 * 128 + sub * 8);
    uint4 p1 = *(const uint4*)(h + (size_t)s1 * 128 + sub * 8);
    uint4 p2 = *(const uint4*)(h + (size_t)s2 * 128 + sub * 8);
    uint4 p3 = *(const uint4*)(h + (size_t)s3 * 128 + sub * 8);
    acc8(a, p0); acc8(a, p1); acc8(a, p2); acc8(a, p3);
  }
  {  // masked final round: all remaining loads issued together
    int j0 = j, j1 = j + 4, j2 = j + 8, j3 = j + 12;
    u32 m0 = (j0 < end) ? 0xffffffffu : 0u;
    u32 m1 = (j1 < end) ? 0xffffffffu : 0u;
    u32 m2 = (j2 < end) ? 0xffffffffu : 0u;
    u32 m3 = (j3 < end) ? 0xffffffffu : 0u;
    int t0 = (j0 < end) ? j0 : 0, t1 = (j1 < end) ? j1 : 0;
    int t2 = (j2 < end) ? j2 : 0, t3 = (j3 < end) ? j3 : 0;
    int s0 = csr[t0], s1 = csr[t1], s2 = csr[t2], s3 = csr[t3];
    uint4 p0 = *(const uint4*)(h + (size_t)s0 * 128 + sub * 8);
    uint4 p1 = *(const uint4*)(h + (size_t)s1 * 128 + sub * 8);
    uint4 p2 = *(const uint4*)(h + (size_t)s2 * 128 + sub * 8);
    uint4 p3 = *(const uint4*)(h + (size_t)s3 * 128 + sub * 8);
    p0.x &= m0; p0.y &= m0; p0.z &= m0; p0.w &= m0;
    p1.x &= m1; p1.y &= m1; p1.z &= m1; p1.w &= m1;
    p2.x &= m2; p2.y &= m2; p2.z &= m2; p2.w &= m2;
    p3.x &= m3; p3.y &= m3; p3.z &= m3; p3.w &= m3;
    acc8(a, p0); acc8(a, p1); acc8(a, p2); acc8(a, p3);
  }
  #pragma unroll
  for (int i = 0; i < 4; ++i) {
    a[i].x += __shfl_xor(a[i].x, 16); a[i].x += __shfl_xor(a[i].x, 32);
    a[i].y += __shfl_xor(a[i].y, 16); a[i].y += __shfl_xor(a[i].y, 32);
  }
  if (q == 0) {
    uint4 o;
    o.x = (u32)f2bf(a[0].x) | ((u32)f2bf(a[0].y) << 16);
    o.y = (u32)f2bf(a[1].x) | ((u32)f2bf(a[1].y) << 16);
    o.z = (u32)f2bf(a[2].x) | ((u32)f2bf(a[2].y) << 16);
    o.w = (u32)f2bf(a[3].x) | ((u32)f2bf(a[3].y) << 16);
    *(uint4*)(s + (size_t)node * 128 + sub * 8) = o;
  }
}

// ---------------- fused dual-GEMM + GRU cell ----------------
// 32 rows/block, 4 waves, wave w owns output cols w*32..+31 (all 4 gates).
// B direct global->VGPR, frag-ordered, 2-kc-ahead rotating prefetch.
// __launch_bounds__(256, 2): 256-VGPR budget -- the ~170-reg live set
// (64 acc + 72 B + misc) fits with slack; at (256,3)'s 170-cap it spills
// to scratch (suspected cause of the 47us-vs-10us-model gap).
__global__ __launch_bounds__(256, 2) void k_gemm_gru(
    const u16* __restrict__ s_mat, const u16* __restrict__ h_mat,
    const u16* __restrict__ bsw, const float* __restrict__ b_ih,
    const float* __restrict__ b_hh, u16* __restrict__ h_out) {
  __shared__ u16 Asw[8192];       // 16 KB: A=[s|h], 32 rows x 256 k, frag-ordered

  const int tid  = threadIdx.x;
  const int wave = tid >> 6;
  const int lane = tid & 63;
  const int nl   = lane & 15;
  const int quad = lane >> 4;
  const int row0 = blockIdx.x * 32;   // 3125 * 32 == 100000 exactly

  {  // stage A
    int snl = tid & 15, squad = (tid >> 4) & 3, sel = tid >> 6;
    int g = sel & 1, half = sel >> 1;
    const u16* row = (half ? h_mat : s_mat) + (size_t)(row0 + g * 16 + snl) * 128;
    #pragma unroll
    for (int kc2 = 0; kc2 < 4; ++kc2) {
      uint4 v = *(const uint4*)(row + kc2 * 32 + squad * 8);
      *(uint4*)&Asw[(((g * 8 + half * 4 + kc2) * 4 + squad) * 16 + snl) * 8] = v;
    }
  }
  __syncthreads();

  const u16* bp = bsw + wave * 8 * 512 + lane * 8;

  f32x4 acc[2][8];
  #pragma unroll
  for (int g = 0; g < 2; ++g)
    #pragma unroll
    for (int u = 0; u < 8; ++u) acc[g][u] = (f32x4){0.f, 0.f, 0.f, 0.f};

  // active slot sets: kc<4 -> {0..3,4,5} (r,z,i_n); kc>=4 -> {0..3,6,7} (r,z,h_n)
  bf16x8 b0[6], b1[6], b2[6];
  #pragma unroll
  for (int i = 0; i < 6; ++i) b0[i] = *(const bf16x8*)(bp + i * 512);                 // kc=0
  #pragma unroll
  for (int i = 0; i < 6; ++i) b1[i] = *(const bf16x8*)(bp + 16384 + i * 512);         // kc=1

  #pragma unroll
  for (int kc = 0; kc < 8; ++kc) {
    if (kc < 6) {  // prefetch kc+2
      #pragma unroll
      for (int i = 0; i < 6; ++i) {
        int us = (kc + 2 < 4) ? i : (i < 4 ? i : i + 2);
        b2[i] = *(const bf16x8*)(bp + (kc + 2) * 16384 + us * 512);
      }
    }
    bf16x8 a0 = *(const bf16x8*)&Asw[kc * 512 + lane * 8];
    bf16x8 a1 = *(const bf16x8*)&Asw[(8 + kc) * 512 + lane * 8];
    #pragma unroll
    for (int i = 0; i < 6; ++i) {
      int u = (kc < 4) ? i : (i < 4 ? i : i + 2);
      acc[0][u] = __builtin_amdgcn_mfma_f32_16x16x32_bf16(a0, b0[i], acc[0][u], 0, 0, 0);
      acc[1][u] = __builtin_amdgcn_mfma_f32_16x16x32_bf16(a1, b0[i], acc[1][u], 0, 0, 0);
    }
    #pragma unroll
    for (int i = 0; i < 6; ++i) { b0[i] = b1[i]; b1[i] = b2[i]; }
  }

  float bias[8];
  #pragma unroll
  for (int u = 0; u < 8; ++u) {
    int gi = u >> 1, hu = u & 1;
    int cw = wave * 32 + hu * 16 + nl;
    bias[u] = (gi == 0) ? b_ih[cw] + b_hh[cw]
            : (gi == 1) ? b_ih[128 + cw] + b_hh[128 + cw]
            : (gi == 2) ? b_ih[256 + cw]
                        : b_hh[256 + cw];
  }

  #pragma unroll
  for (int g = 0; g < 2; ++g) {
    #pragma unroll
    for (int hu = 0; hu < 2; ++hu) {
      int cw = wave * 32 + hu * 16 + nl;
      int hbase = ((g * 8 + 4 + wave) * 4 + ((hu * 2 + (nl >> 3)) & 3)) * 128 + (nl & 7);
      #pragma unroll
      for (int i = 0; i < 4; ++i) {
        int m = quad * 4 + i;
        float rv = sig_f(acc[g][0 + hu][i] + bias[0 + hu]);
        float zv = sig_f(acc[g][2 + hu][i] + bias[2 + hu]);
        float iv = acc[g][4 + hu][i] + bias[4 + hu];
        float hn = acc[g][6 + hu][i] + bias[6 + hu];
        float hv = bf2f(Asw[hbase + m * 8]);
        float n  = tanh_f(iv + rv * hn);
        float o  = n + zv * (hv - n);
        h_out[(size_t)(row0 + g * 16 + m) * 128 + cw] = f2bf(o);
      }
    }
  }
}

// ---------------- relu + segment mean pool (two-phase, parallel) ----------------
__global__ void k_pool_partial(const u16* __restrict__ h, const int* __restrict__ batch,
                               float* __restrict__ acc) {
  int t = threadIdx.x;  // column 0..127
  int node0 = blockIdx.x * 125;
  int node1 = node0 + 125;
  int cur = batch[node0];
  float sum = 0.f;
  for (int r = node0; r < node1; ++r) {
    int g = batch[r];
    if (g != cur) {
      atomicAdd(&acc[cur * 128 + t], sum);
      sum = 0.f;
      cur = g;
    }
    sum += fmaxf(bf2f(h[(size_t)r * 128 + t]), 0.f);
  }
  atomicAdd(&acc[cur * 128 + t], sum);
}

__global__ void k_pool_div(const float* __restrict__ acc, const int* __restrict__ batch,
                           float* __restrict__ out) {
  __shared__ int se[2];
  int g = blockIdx.x, t = threadIdx.x;
  if (t < 2) {
    int target = g + t;
    int lo = 0, hi = N_NODES;
    while (lo < hi) { int mid = (lo + hi) >> 1; if (batch[mid] < target) lo = mid + 1; else hi = mid; }
    se[t] = lo;
  }
  __syncthreads();
  int cnt = se[1] - se[0];
  out[g * 128 + t] = acc[g * 128 + t] / (float)(cnt > 0 ? cnt : 1);
}

extern "C" void kernel_launch(void* const* d_in, const int* in_sizes, int n_in,
                              void* d_out, int out_size, void* d_ws, size_t ws_size,
                              hipStream_t stream) {
  const float* x     = (const float*)d_in[0];
  const int*   edges = (const int*)d_in[1];
  const int*   batch = (const int*)d_in[2];
  const float* W     = (const float*)d_in[3];
  const float* w_ih  = (const float*)d_in[4];
  const float* w_hh  = (const float*)d_in[5];
  const float* b_ih  = (const float*)d_in[6];
  const float* b_hh  = (const float*)d_in[7];
  float* out = (float*)d_out;

  char* w = (char*)d_ws;
  u16* buf0    = (u16*)(w);                 // 25,600,000 B  (h / s ping)
  u16* buf1    = (u16*)(w + 25600000);      // 25,600,000 B  (h / s pong)
  u16* bsw     = (u16*)(w + 51200000);      // 1,048,576 B
  float* acc   = (float*)(w + 52300032);    // 32,768 B  (pool accumulator)
  int* offs    = (int*)(w + 52710400);      // 400,004 B
  int* gcursor = (int*)(w + 53120768);      // 1,024 B
  int* ebase   = (int*)(w + 53123328);      // 1,028 B
  int* csr     = (int*)(w + 53531136);      // 6,400,000 B  -> total ~60 MB
  u32* ebuf    = (u32*)buf1;                // 256*7168*4 = 7.3 MB; buf1 dead until 1st gather

  const int* esrc = edges;
  const int* edst = edges + N_EDGES;

  hipMemsetAsync(gcursor, 0, NBUCK * sizeof(int), stream);
  k_part<<<391, 1024, 0, stream>>>(esrc, edst, gcursor, ebuf);
  k_bscan<<<1, NBUCK, 0, stream>>>(gcursor, ebase);
  k_csr<<<NBUCK, 1024, 0, stream>>>(ebuf, ebase, offs, csr);
  k_wb<<<1024, 128, 0, stream>>>(W, w_ih, w_hh, bsw);
  k_convert<<<(N_NODES * HIDDEN) / 1024, 256, 0, stream>>>(x, buf0);
  hipMemsetAsync(acc, 0, N_GRAPHS * HIDDEN * sizeof(float), stream);

  u16* hcur = buf0;
  u16* hnxt = buf1;
  for (int st = 0; st < STEPS; ++st) {
    k_gather<<<N_NODES / 4, 256, 0, stream>>>(hcur, csr, offs, hnxt);
    // in-place: each block reads only its own 32 rows of s (hnxt) and h (hcur)
    // into LDS before writing h_out (hnxt) over those same rows.
    k_gemm_gru<<<N_NODES / 32, 256, 0, stream>>>(hnxt, hcur, bsw + st * 131072,
                                                 b_ih, b_hh, hnxt);
    u16* tmp = hcur; hcur = hnxt; hnxt = tmp;
  }
  k_pool_partial<<<800, 128, 0, stream>>>(hcur, batch, acc);
  k_pool_div<<<N_GRAPHS, 128, 0, stream>>>(acc, batch, out);
}

// Round 16
// 582.970 us; speedup vs baseline: 1.0078x; 1.0078x over previous
//
#include <hip/hip_runtime.h>

#define N_NODES  100000
#define N_EDGES  1600000
#define HIDDEN   128
#define STEPS    4
#define N_GRAPHS 64
#define NBUCK    256
#define BWID     391   // nodes per bucket: 256*391 = 100096 >= 100000 (<512 -> 9 bits)
#define BCAP     7168  // fixed ebuf slots per bucket (mean 6250, +11 sigma)

typedef unsigned short u16;
typedef unsigned int   u32;
typedef unsigned long long u64;
typedef __attribute__((ext_vector_type(8))) short bf16x8;
typedef __attribute__((ext_vector_type(4))) float f32x4;
typedef __attribute__((ext_vector_type(2))) float f32x2;

__device__ inline u16 f2bf(float f) {
  u32 u = __float_as_uint(f);
  u = (u + 0x7FFFu + ((u >> 16) & 1u)) >> 16;  // RTNE
  return (u16)u;
}
__device__ inline float bf2f(u16 b) { return __uint_as_float(((u32)b) << 16); }

// rcp-based activations: no IEEE division sequence, no clamps.
__device__ inline float rcp_f(float x) { return __builtin_amdgcn_rcpf(x); }
__device__ inline float sig_f(float x) { return rcp_f(1.f + __expf(-x)); }
__device__ inline float tanh_f(float x) { return 1.f - 2.f * rcp_f(1.f + __expf(2.f * x)); }

// ---------------- CSR build (bucketed multisplit, fixed-capacity buckets) ----------------
// ebuf entries are u32: (dst_local << 17) | src   (dst_local < 391, src < 2^17)
// Per-WAVE histograms: 64 lanes into 256 buckets -> ~no LDS-atomic serialization
// (vs 1024 threads hammering one 256-bucket histogram).
__global__ __launch_bounds__(1024) void k_part(const int* __restrict__ esrc,
                                               const int* __restrict__ edst,
                                               int* __restrict__ gcursor,
                                               u32* __restrict__ ebuf) {
  __shared__ int hist[16][NBUCK];   // 16 KB
  __shared__ int base[16][NBUCK];   // 16 KB
  int tid = threadIdx.x;
  int wv  = tid >> 6;
  #pragma unroll
  for (int i = 0; i < 4; ++i) ((int*)hist)[tid + i * 1024] = 0;
  __syncthreads();
  int e0 = blockIdx.x * 4096;
  int sv[4], dv[4], bk[4], rk[4];
  #pragma unroll
  for (int i = 0; i < 4; ++i) {
    int e = e0 + i * 1024 + tid;
    if (e < N_EDGES) {
      sv[i] = esrc[e];
      dv[i] = edst[e];
      bk[i] = (int)((u32)dv[i] / (u32)BWID);
      rk[i] = atomicAdd(&hist[wv][bk[i]], 1);
    } else bk[i] = -1;
  }
  __syncthreads();
  if (tid < NBUCK) {
    int c[16];
    int sum = 0;
    #pragma unroll
    for (int w = 0; w < 16; ++w) { c[w] = hist[w][tid]; sum += c[w]; }
    int g = atomicAdd(&gcursor[tid], sum);
    #pragma unroll
    for (int w = 0; w < 16; ++w) { base[w][tid] = g; g += c[w]; }
  }
  __syncthreads();
  #pragma unroll
  for (int i = 0; i < 4; ++i) {
    if (bk[i] >= 0) {
      int pos = bk[i] * BCAP + base[wv][bk[i]] + rk[i];
      ebuf[pos] = ((u32)(dv[i] - bk[i] * BWID) << 17) | (u32)sv[i];
    }
  }
}

// Scan bucket counts -> ebase; also zero the pool accumulator (saves a dispatch).
__global__ void k_bscan(const int* __restrict__ gcursor, int* __restrict__ ebase,
                        float* __restrict__ acc) {
  __shared__ int buf[NBUCK];
  int t = threadIdx.x;
  int v = gcursor[t];
  buf[t] = v;
  __syncthreads();
  for (int off = 1; off < NBUCK; off <<= 1) {
    int u = 0;
    if (t >= off) u = buf[t - off];
    __syncthreads();
    buf[t] += u;
    __syncthreads();
  }
  ebase[t] = buf[t] - v;
  if (t == NBUCK - 1) ebase[NBUCK] = buf[t];
  for (int i = t; i < N_GRAPHS * HIDDEN; i += NBUCK) acc[i] = 0.f;
}

__global__ __launch_bounds__(1024) void k_csr(const u32* __restrict__ ebuf,
                                              const int* __restrict__ ebase,
                                              int* __restrict__ offs,
                                              int* __restrict__ csr) {
  __shared__ int lcnt[512];
  __shared__ int lofs[512];
  int b = blockIdx.x, tid = threadIdx.x;
  int n0 = b * BWID;
  int n1 = min(n0 + BWID, N_NODES);
  int nn = n1 - n0;
  int e0 = ebase[b];
  int cnt = ebase[b + 1] - e0;
  const u32* ebase_p = ebuf + (size_t)b * BCAP;
  if (tid < 512) lcnt[tid] = 0;
  __syncthreads();
  for (int e = tid; e < cnt; e += 1024) {
    int dst = (int)(ebase_p[e] >> 17);   // bucket-local
    atomicAdd(&lcnt[dst], 1);
  }
  __syncthreads();
  if (tid < 512) lofs[tid] = lcnt[tid];
  __syncthreads();
  for (int off = 1; off < 512; off <<= 1) {
    int v = 0;
    if (tid < 512 && tid >= off) v = lofs[tid - off];
    __syncthreads();
    if (tid < 512 && tid >= off) lofs[tid] += v;
    __syncthreads();
  }
  int nodeoff = 0;
  if (tid < 512) nodeoff = e0 + lofs[tid] - lcnt[tid];  // exclusive
  if (tid < 512) lofs[tid] = nodeoff;                   // reuse as cursor
  if (tid < nn) offs[n0 + tid] = nodeoff;
  if (b == 0 && tid == 0) offs[N_NODES] = N_EDGES;
  __syncthreads();
  for (int e = tid; e < cnt; e += 1024) {
    u32 p = ebase_p[e];
    int src = (int)(p & 0x1FFFFu);
    int dst = (int)(p >> 17);
    int pos = atomicAdd(&lofs[dst], 1);
    csr[pos] = src;
  }
}

// ---------------- combined weight build ----------------
__global__ void k_wb(const float* __restrict__ W, const float* __restrict__ w_ih,
                     const float* __restrict__ w_hh, u16* __restrict__ bsw) {
  __shared__ float wrow[128];
  int b = blockIdx.x, st = b >> 8, k = b & 255, t = threadIdx.x;
  if (k < 128) wrow[t] = W[(st * 128 + k) * 128 + t];
  __syncthreads();
  int kc = k >> 5, quad = (k >> 3) & 3, kl = k & 7;
  u16* base = bsw + (size_t)st * 131072 + kc * 16384;
  #pragma unroll
  for (int gq = 0; gq < 4; ++gq) {
    int c = gq * 128 + t;
    float v;
    if (k < 128) {
      if (c < 384) {
        const float* wr = w_ih + c * 128;
        float sacc = 0.f;
        for (int j = 0; j < 128; ++j) sacc += wrow[j] * wr[j];
        v = sacc;
      } else v = 0.f;
    } else {
      int kk = k - 128;
      if (c < 256)      v = w_hh[c * 128 + kk];
      else if (c < 384) v = 0.f;
      else              v = w_hh[(c - 128) * 128 + kk];
    }
    int gi = c >> 7, cw = c & 127;
    int wv = cw >> 5, hu = (cw >> 4) & 1, nl = c & 15;
    int slot = wv * 8 + gi * 2 + hu;
    base[(slot * 4 + quad) * 128 + nl * 8 + kl] = f2bf(v);
  }
}

// ---------------- x -> bf16 (+ zero the dummy rows of both buffers) ----------------
__global__ void k_convert(const float* __restrict__ x, u16* __restrict__ h0,
                          u16* __restrict__ h1) {
  int i = (blockIdx.x * 256 + threadIdx.x) * 4;
  float4 v = *(const float4*)(x + i);
  u16 o[4] = {f2bf(v.x), f2bf(v.y), f2bf(v.z), f2bf(v.w)};
  *(uint2*)(h0 + i) = *(uint2*)o;
  if (blockIdx.x == 0) {
    int t = threadIdx.x;
    if (t < 64)       ((u32*)(h0 + (size_t)N_NODES * 128))[t] = 0;
    else if (t < 128) ((u32*)(h1 + (size_t)N_NODES * 128))[t - 64] = 0;
  }
}

// ---------------- neighbor gather-sum: s[dst] = sum h[src] ----------------
// One node per wave; quarter-wave q takes edges j = beg+q+4t. All row addresses
// are u32 offsets (src<<8 | colofs) off the SGPR base -> 1 VALU per row.
// Tail: OOB slots redirect to the all-zero dummy row (index N_NODES) via one
// cndmask -- no value masking. Accumulation in float2 -> v_pk_add_f32.
__device__ inline void acc8(f32x2* a, uint4 p) {
  f32x2 v;
  v.x = __uint_as_float(p.x << 16); v.y = __uint_as_float(p.x & 0xffff0000u);
  a[0] += v;
  v.x = __uint_as_float(p.y << 16); v.y = __uint_as_float(p.y & 0xffff0000u);
  a[1] += v;
  v.x = __uint_as_float(p.z << 16); v.y = __uint_as_float(p.z & 0xffff0000u);
  a[2] += v;
  v.x = __uint_as_float(p.w << 16); v.y = __uint_as_float(p.w & 0xffff0000u);
  a[3] += v;
}
__device__ inline uint4 ldrow(const char* hb, u32 off) {
  return *(const uint4*)(hb + off);
}

__global__ void k_gather(const u16* __restrict__ h, const int* __restrict__ csr,
                         const int* __restrict__ offs, u16* __restrict__ s) {
  int node = blockIdx.x * 4 + (threadIdx.x >> 6);
  int lane = threadIdx.x & 63;
  int q   = lane >> 4;
  int sub = lane & 15;
  const char* hb = (const char*)h;
  u32 co = (u32)(sub * 16);
  int beg = offs[node], end = offs[node + 1];
  f32x2 a[4];
  a[0] = a[1] = a[2] = a[3] = (f32x2){0.f, 0.f};
  int j = beg + q;
  for (; j + 12 < end; j += 16) {
    u32 s0 = (u32)csr[j], s1 = (u32)csr[j + 4], s2 = (u32)csr[j + 8], s3 = (u32)csr[j + 12];
    uint4 p0 = ldrow(hb, (s0 << 8) | co);
    uint4 p1 = ldrow(hb, (s1 << 8) | co);
    uint4 p2 = ldrow(hb, (s2 << 8) | co);
    uint4 p3 = ldrow(hb, (s3 << 8) | co);
    acc8(a, p0); acc8(a, p1); acc8(a, p2); acc8(a, p3);
  }
  {  // tail: redirect OOB slots to the zero dummy row (one cndmask each)
    int j0 = j, j1 = j + 4, j2 = j + 8, j3 = j + 12;
    int t0 = (j0 < end) ? j0 : 0, t1 = (j1 < end) ? j1 : 0;
    int t2 = (j2 < end) ? j2 : 0, t3 = (j3 < end) ? j3 : 0;
    u32 s0 = (u32)csr[t0]; s0 = (j0 < end) ? s0 : (u32)N_NODES;
    u32 s1 = (u32)csr[t1]; s1 = (j1 < end) ? s1 : (u32)N_NODES;
    u32 s2 = (u32)csr[t2]; s2 = (j2 < end) ? s2 : (u32)N_NODES;
    u32 s3 = (u32)csr[t3]; s3 = (j3 < end) ? s3 : (u32)N_NODES;
    uint4 p0 = ldrow(hb, (s0 << 8) | co);
    uint4 p1 = ldrow(hb, (s1 << 8) | co);
    uint4 p2 = ldrow(hb, (s2 << 8) | co);
    uint4 p3 = ldrow(hb, (s3 << 8) | co);
    acc8(a, p0); acc8(a, p1); acc8(a, p2); acc8(a, p3);
  }
  #pragma unroll
  for (int i = 0; i < 4; ++i) {
    a[i].x += __shfl_xor(a[i].x, 16); a[i].x += __shfl_xor(a[i].x, 32);
    a[i].y += __shfl_xor(a[i].y, 16); a[i].y += __shfl_xor(a[i].y, 32);
  }
  if (q == 0) {
    uint4 o;
    o.x = (u32)f2bf(a[0].x) | ((u32)f2bf(a[0].y) << 16);
    o.y = (u32)f2bf(a[1].x) | ((u32)f2bf(a[1].y) << 16);
    o.z = (u32)f2bf(a[2].x) | ((u32)f2bf(a[2].y) << 16);
    o.w = (u32)f2bf(a[3].x) | ((u32)f2bf(a[3].y) << 16);
    *(uint4*)(s + (size_t)node * 128 + sub * 8) = o;
  }
}

// ---------------- fused dual-GEMM + GRU cell (R15-frozen) ----------------
__global__ __launch_bounds__(256, 2) void k_gemm_gru(
    const u16* __restrict__ s_mat, const u16* __restrict__ h_mat,
    const u16* __restrict__ bsw, const float* __restrict__ b_ih,
    const float* __restrict__ b_hh, u16* __restrict__ h_out) {
  __shared__ u16 Asw[8192];       // 16 KB: A=[s|h], 32 rows x 256 k, frag-ordered

  const int tid  = threadIdx.x;
  const int wave = tid >> 6;
  const int lane = tid & 63;
  const int nl   = lane & 15;
  const int quad = lane >> 4;
  const int row0 = blockIdx.x * 32;   // 3125 * 32 == 100000 exactly

  {  // stage A
    int snl = tid & 15, squad = (tid >> 4) & 3, sel = tid >> 6;
    int g = sel & 1, half = sel >> 1;
    const u16* row = (half ? h_mat : s_mat) + (size_t)(row0 + g * 16 + snl) * 128;
    #pragma unroll
    for (int kc2 = 0; kc2 < 4; ++kc2) {
      uint4 v = *(const uint4*)(row + kc2 * 32 + squad * 8);
      *(uint4*)&Asw[(((g * 8 + half * 4 + kc2) * 4 + squad) * 16 + snl) * 8] = v;
    }
  }
  __syncthreads();

  const u16* bp = bsw + wave * 8 * 512 + lane * 8;

  f32x4 acc[2][8];
  #pragma unroll
  for (int g = 0; g < 2; ++g)
    #pragma unroll
    for (int u = 0; u < 8; ++u) acc[g][u] = (f32x4){0.f, 0.f, 0.f, 0.f};

  bf16x8 b0[6], b1[6], b2[6];
  #pragma unroll
  for (int i = 0; i < 6; ++i) b0[i] = *(const bf16x8*)(bp + i * 512);
  #pragma unroll
  for (int i = 0; i < 6; ++i) b1[i] = *(const bf16x8*)(bp + 16384 + i * 512);

  #pragma unroll
  for (int kc = 0; kc < 8; ++kc) {
    if (kc < 6) {
      #pragma unroll
      for (int i = 0; i < 6; ++i) {
        int us = (kc + 2 < 4) ? i : (i < 4 ? i : i + 2);
        b2[i] = *(const bf16x8*)(bp + (kc + 2) * 16384 + us * 512);
      }
    }
    bf16x8 a0 = *(const bf16x8*)&Asw[kc * 512 + lane * 8];
    bf16x8 a1 = *(const bf16x8*)&Asw[(8 + kc) * 512 + lane * 8];
    #pragma unroll
    for (int i = 0; i < 6; ++i) {
      int u = (kc < 4) ? i : (i < 4 ? i : i + 2);
      acc[0][u] = __builtin_amdgcn_mfma_f32_16x16x32_bf16(a0, b0[i], acc[0][u], 0, 0, 0);
      acc[1][u] = __builtin_amdgcn_mfma_f32_16x16x32_bf16(a1, b0[i], acc[1][u], 0, 0, 0);
    }
    #pragma unroll
    for (int i = 0; i < 6; ++i) { b0[i] = b1[i]; b1[i] = b2[i]; }
  }

  float bias[8];
  #pragma unroll
  for (int u = 0; u < 8; ++u) {
    int gi = u >> 1, hu = u & 1;
    int cw = wave * 32 + hu * 16 + nl;
    bias[u] = (gi == 0) ? b_ih[cw] + b_hh[cw]
            : (gi == 1) ? b_ih[128 + cw] + b_hh[128 + cw]
            : (gi == 2) ? b_ih[256 + cw]
                        : b_hh[256 + cw];
  }

  #pragma unroll
  for (int g = 0; g < 2; ++g) {
    #pragma unroll
    for (int hu = 0; hu < 2; ++hu) {
      int cw = wave * 32 + hu * 16 + nl;
      int hbase = ((g * 8 + 4 + wave) * 4 + ((hu * 2 + (nl >> 3)) & 3)) * 128 + (nl & 7);
      #pragma unroll
      for (int i = 0; i < 4; ++i) {
        int m = quad * 4 + i;
        float rv = sig_f(acc[g][0 + hu][i] + bias[0 + hu]);
        float zv = sig_f(acc[g][2 + hu][i] + bias[2 + hu]);
        float iv = acc[g][4 + hu][i] + bias[4 + hu];
        float hn = acc[g][6 + hu][i] + bias[6 + hu];
        float hv = bf2f(Asw[hbase + m * 8]);
        float n  = tanh_f(iv + rv * hn);
        float o  = n + zv * (hv - n);
        h_out[(size_t)(row0 + g * 16 + m) * 128 + cw] = f2bf(o);
      }
    }
  }
}

// ---------------- relu + segment mean pool (two-phase, parallel) ----------------
__global__ void k_pool_partial(const u16* __restrict__ h, const int* __restrict__ batch,
                               float* __restrict__ acc) {
  int t = threadIdx.x;  // column 0..127
  int node0 = blockIdx.x * 125;
  int node1 = node0 + 125;
  int cur = batch[node0];
  float sum = 0.f;
  for (int r = node0; r < node1; ++r) {
    int g = batch[r];
    if (g != cur) {
      atomicAdd(&acc[cur * 128 + t], sum);
      sum = 0.f;
      cur = g;
    }
    sum += fmaxf(bf2f(h[(size_t)r * 128 + t]), 0.f);
  }
  atomicAdd(&acc[cur * 128 + t], sum);
}

__global__ void k_pool_div(const float* __restrict__ acc, const int* __restrict__ batch,
                           float* __restrict__ out) {
  __shared__ int se[2];
  int g = blockIdx.x, t = threadIdx.x;
  if (t < 2) {
    int target = g + t;
    int lo = 0, hi = N_NODES;
    while (lo < hi) { int mid = (lo + hi) >> 1; if (batch[mid] < target) lo = mid + 1; else hi = mid; }
    se[t] = lo;
  }
  __syncthreads();
  int cnt = se[1] - se[0];
  out[g * 128 + t] = acc[g * 128 + t] / (float)(cnt > 0 ? cnt : 1);
}

extern "C" void kernel_launch(void* const* d_in, const int* in_sizes, int n_in,
                              void* d_out, int out_size, void* d_ws, size_t ws_size,
                              hipStream_t stream) {
  const float* x     = (const float*)d_in[0];
  const int*   edges = (const int*)d_in[1];
  const int*   batch = (const int*)d_in[2];
  const float* W     = (const float*)d_in[3];
  const float* w_ih  = (const float*)d_in[4];
  const float* w_hh  = (const float*)d_in[5];
  const float* b_ih  = (const float*)d_in[6];
  const float* b_hh  = (const float*)d_in[7];
  float* out = (float*)d_out;

  char* w = (char*)d_ws;
  u16* buf0    = (u16*)(w);                 // 25,600,256 B (h/s ping + zero dummy row)
  u16* buf1    = (u16*)(w + 25600256);      // 25,600,256 B (h/s pong + zero dummy row)
  u16* bsw     = (u16*)(w + 51200512);      // 1,048,576 B
  float* acc   = (float*)(w + 52249088);    // 32,768 B  (pool accumulator)
  int* offs    = (int*)(w + 52281856);      // 400,004 B
  int* gcursor = (int*)(w + 52682240);      // 1,024 B
  int* ebase   = (int*)(w + 52683264);      // 1,028 B
  int* csr     = (int*)(w + 52684800);      // 6,400,000 B -> total ~59.1 MB
  u32* ebuf    = (u32*)buf1;                // 7.3 MB; no overlap with buf1 dummy row

  const int* esrc = edges;
  const int* edst = edges + N_EDGES;

  hipMemsetAsync(gcursor, 0, NBUCK * sizeof(int), stream);
  k_part<<<391, 1024, 0, stream>>>(esrc, edst, gcursor, ebuf);
  k_bscan<<<1, NBUCK, 0, stream>>>(gcursor, ebase, acc);
  k_csr<<<NBUCK, 1024, 0, stream>>>(ebuf, ebase, offs, csr);
  k_wb<<<1024, 128, 0, stream>>>(W, w_ih, w_hh, bsw);
  k_convert<<<(N_NODES * HIDDEN) / 1024, 256, 0, stream>>>(x, buf0, buf1);

  u16* hcur = buf0;
  u16* hnxt = buf1;
  for (int st = 0; st < STEPS; ++st) {
    k_gather<<<N_NODES / 4, 256, 0, stream>>>(hcur, csr, offs, hnxt);
    // in-place: each block reads only its own 32 rows of s (hnxt) and h (hcur)
    // into LDS before writing h_out (hnxt) over those same rows.
    k_gemm_gru<<<N_NODES / 32, 256, 0, stream>>>(hnxt, hcur, bsw + st * 131072,
                                                 b_ih, b_hh, hnxt);
    u16* tmp = hcur; hcur = hnxt; hnxt = tmp;
  }
  k_pool_partial<<<800, 128, 0, stream>>>(hcur, batch, acc);
  k_pool_div<<<N_GRAPHS, 128, 0, stream>>>(acc, batch, out);
}